// Round 3
// baseline (95053.772 us; speedup 1.0000x reference)
//
#include <hip/hip_runtime.h>
#include <math.h>

#define B 32
#define S 512
#define T 128
#define V 32000
#define H 512
#define NB 256          // persistent grid size (== CU count, co-resident)
#define NT 256
#define LCHUNK 250      // logits chunks: 250 blocks x 128 rows = 32000
#define LROWS 128
#define LDSPITCH 264    // 256 k-floats + 8 pad, 16B aligned

__device__ __forceinline__ float dot4(float acc, float4 a, float4 b){
    return fmaf(a.x,b.x, fmaf(a.y,b.y, fmaf(a.z,b.z, fmaf(a.w,b.w, acc))));
}
__device__ __forceinline__ float sigmoidf_(float x){ return 1.0f/(1.0f+expf(-x)); }

// device-wide barrier: release + arrive (device-scope atomic) + spin + acquire.
// Grid must be co-resident (NB == 256 blocks, 1/CU guaranteed).
__device__ __forceinline__ void grid_sync(unsigned* bar, unsigned target){
    __threadfence();                    // release: drain stores to coherence point
    __syncthreads();
    if (threadIdx.x == 0){
        __hip_atomic_fetch_add(bar, 1u, __ATOMIC_RELEASE, __HIP_MEMORY_SCOPE_AGENT);
        int guard = 0;
        while (__hip_atomic_load(bar, __ATOMIC_ACQUIRE, __HIP_MEMORY_SCOPE_AGENT) < target){
            __builtin_amdgcn_s_sleep(1);
            if (++guard > 50000000) break;   // anti-hang safety valve
        }
    }
    __syncthreads();
    __threadfence();                    // acquire: invalidate stale L1/L2
}

// ================= persistent encoder: 512 steps, 1 barrier/step =============
// 256 blocks: bk&1 = dir, bk>>1 = j-group (4 j each).
// 256 threads: b = tid&31, jj = (tid>>5)&3, kh = tid>>7 (K split 2x256).
__global__ __launch_bounds__(NT, 1) void enc_persistent(
    const int* __restrict__ input_seq, const float* __restrict__ emb,
    const float* __restrict__ fWih, const float* __restrict__ fWhh,
    const float* __restrict__ fbih, const float* __restrict__ fbhh,
    const float* __restrict__ bWih, const float* __restrict__ bWhh,
    const float* __restrict__ bbih, const float* __restrict__ bbhh,
    float* enc_out, float* out_b, float* hdec, unsigned* bar)
{
    __shared__ float shp[128*6];
    const int bk = blockIdx.x, tid = threadIdx.x;
    const int dir = bk & 1, jg = bk >> 1;
    const int b = tid & 31, jj = (tid>>5)&3, kh = tid>>7;
    const int j = jg*4 + jj;

    const float *Wih = dir? bWih : fWih;
    const float *Whh = dir? bWhh : fWhh;
    const float *bih = dir? bbih : fbih;
    const float *bhh = dir? bbhh : fbhh;
    float* outp = dir? out_b : enc_out;

    const float4* wir = (const float4*)(Wih + (size_t)(j      )*H + kh*256);
    const float4* wiz = (const float4*)(Wih + (size_t)(j +   H)*H + kh*256);
    const float4* win = (const float4*)(Wih + (size_t)(j + 2*H)*H + kh*256);
    const float4* whr = (const float4*)(Whh + (size_t)(j      )*H + kh*256);
    const float4* whz = (const float4*)(Whh + (size_t)(j +   H)*H + kh*256);
    const float4* whn = (const float4*)(Whh + (size_t)(j + 2*H)*H + kh*256);
    const float bi_r = bih[j], bi_z = bih[H+j], bi_n = bih[2*H+j];
    const float bh_r = bhh[j], bh_z = bhh[H+j], bh_n = bhh[2*H+j];

    unsigned tgt_bar = 0;
    for (int t=0; t<S; t++){
        const int pos  = dir ? (S-1-t) : t;
        const int hpos = dir ? (S-t)   : (t-1);
        const int tokb = input_seq[b*S + pos];
        const float4* x4 = (const float4*)(emb + (size_t)tokb*H + kh*256);

        float ir=0.f, iz=0.f, in_=0.f, hr=0.f, hz=0.f, hn=0.f;
        if (t > 0){
            const float4* h4 = (const float4*)(outp + ((size_t)b*S + hpos)*H + kh*256);
            #pragma unroll 4
            for (int k=0;k<64;k++){
                const float4 xv = x4[k], hv = h4[k];
                ir  = dot4(ir , xv, wir[k]);
                iz  = dot4(iz , xv, wiz[k]);
                in_ = dot4(in_, xv, win[k]);
                hr  = dot4(hr , hv, whr[k]);
                hz  = dot4(hz , hv, whz[k]);
                hn  = dot4(hn , hv, whn[k]);
            }
        } else {
            #pragma unroll 4
            for (int k=0;k<64;k++){
                const float4 xv = x4[k];
                ir  = dot4(ir , xv, wir[k]);
                iz  = dot4(iz , xv, wiz[k]);
                in_ = dot4(in_, xv, win[k]);
            }
        }
        if (kh){
            float* p = shp + (jj*32 + b)*6;
            p[0]=ir; p[1]=iz; p[2]=in_; p[3]=hr; p[4]=hz; p[5]=hn;
        }
        __syncthreads();
        if (!kh){
            const float* p = shp + (jj*32 + b)*6;
            ir+=p[0]; iz+=p[1]; in_+=p[2]; hr+=p[3]; hz+=p[4]; hn+=p[5];
            float hprev = 0.f;
            if (t > 0) hprev = outp[((size_t)b*S + hpos)*H + j];
            const float r = sigmoidf_(ir + bi_r + hr + bh_r);
            const float z = sigmoidf_(iz + bi_z + hz + bh_z);
            const float n = tanhf(in_ + bi_n + r*(hn + bh_n));
            outp[((size_t)b*S + pos)*H + j] = (1.0f - z)*n + z*hprev;
        }
        tgt_bar += NB;
        grid_sync(bar, tgt_bar);
    }
    // tail: hdec0 = hf_last + hb_last (pre-combine values)
    const int gid = bk*NT + tid;
    if (gid < B*H){
        const int bb = gid >> 9, jq = gid & 511;
        hdec[gid] = enc_out[((size_t)bb*S + (S-1))*H + jq] + out_b[((size_t)bb*S)*H + jq];
    }
}

// ================= persistent decoder: 128 steps x 5 phases ==================
__global__ __launch_bounds__(NT, 1) void dec_persistent(
    const int* __restrict__ target_seq, const float* __restrict__ emb,
    const float* __restrict__ dWih, const float* __restrict__ dWhh,
    const float* __restrict__ dbih, const float* __restrict__ dbhh,
    const float* __restrict__ attW, const float* __restrict__ attb,
    const float* __restrict__ outW, const float* __restrict__ outBias,
    float* enc_out, const float* out_b,
    float* hdec, float* scores, float* ctxb, float* att_out,
    float* pm, float* ps, int* pidx, float* lossb,
    float* out, unsigned* bar)
{
    __shared__ __align__(16) float smem[32*LDSPITCH];
    __shared__ int sh_tok[B];
    const int bk = blockIdx.x, tid = threadIdx.x;
    unsigned tgt_bar = 0;

    // ---- combine enc_out += out_b ; init loss ----
    {
        float4* e4 = (float4*)enc_out; const float4* o4 = (const float4*)out_b;
        for (size_t i = (size_t)bk*NT + tid; i < (size_t)B*S*H/4; i += (size_t)NB*NT){
            float4 x = e4[i]; const float4 y = o4[i];
            x.x+=y.x; x.y+=y.y; x.z+=y.z; x.w+=y.w; e4[i]=x;
        }
        if (bk==0 && tid<B) lossb[tid] = 0.0f;
    }
    tgt_bar += NB; grid_sync(bar, tgt_bar);

    // hoisted per-thread constants (G and P phases share index decomposition)
    const int gb = tid & 31, gj = (tid>>5)&1, gkq = tid>>6;
    const int jrow = bk*2 + gj;                 // GRU output col == proj row
    const float4* gwir = (const float4*)(dWih + (size_t)(jrow      )*H + gkq*128);
    const float4* gwiz = (const float4*)(dWih + (size_t)(jrow +   H)*H + gkq*128);
    const float4* gwin = (const float4*)(dWih + (size_t)(jrow + 2*H)*H + gkq*128);
    const float4* gwhr = (const float4*)(dWhh + (size_t)(jrow      )*H + gkq*128);
    const float4* gwhz = (const float4*)(dWhh + (size_t)(jrow +   H)*H + gkq*128);
    const float4* gwhn = (const float4*)(dWhh + (size_t)(jrow + 2*H)*H + gkq*128);
    const float gbi_r = dbih[jrow], gbi_z = dbih[H+jrow], gbi_n = dbih[2*H+jrow];
    const float gbh_r = dbhh[jrow], gbh_z = dbhh[H+jrow], gbh_n = dbhh[2*H+jrow];
    const float4* pw = (const float4*)(attW + (size_t)jrow*(2*H) + gkq*256);

    for (int t=0; t<T; t++){
        float* hin  = hdec + (size_t)(t&1)*B*H;
        float* hout = hdec + (size_t)((t+1)&1)*B*H;

        // ---------- phase G: merge(t-1) -> tokens (+loss by blk0), then GRU --
        if (t == 0){
            if (tid < B) sh_tok[tid] = 1;     // SOS
        } else {
            const int mb = tid>>3, p = tid&7;
            float bv = -INFINITY; int ai = 0x7FFFFFFF;
            for (int c=p; c<LCHUNK; c+=8){
                const float v = pm[mb*LCHUNK + c];
                if (v > bv){ bv = v; ai = pidx[mb*LCHUNK + c]; }
            }
            #pragma unroll
            for (int m=1; m<8; m<<=1){
                const float ov = __shfl_xor(bv, m); const int oi = __shfl_xor(ai, m);
                if (ov > bv || (ov == bv && oi < ai)){ bv = ov; ai = oi; }
            }
            if (p==0) sh_tok[mb] = ai;
            if (bk == 0){
                float mm = -INFINITY;
                for (int c=p; c<LCHUNK; c+=8) mm = fmaxf(mm, pm[mb*LCHUNK+c]);
                #pragma unroll
                for (int m=1;m<8;m<<=1) mm = fmaxf(mm, __shfl_xor(mm, m));
                float se = 0.0f;
                for (int c=p; c<LCHUNK; c+=8) se += ps[mb*LCHUNK+c]*expf(pm[mb*LCHUNK+c]-mm);
                #pragma unroll
                for (int m=1;m<8;m<<=1) se += __shfl_xor(se, m);
                const int tg = target_seq[mb*T + (t-1)];
                const float4* ar = (const float4*)(att_out + (size_t)mb*H) + p*16;
                const float4* wr = (const float4*)(outW + (size_t)tg*H) + p*16;
                float d = 0.0f;
                #pragma unroll
                for (int k=0;k<16;k++) d = dot4(d, ar[k], wr[k]);
                #pragma unroll
                for (int m=1;m<8;m<<=1) d += __shfl_xor(d, m);
                if (p==0) lossb[mb] += (mm + logf(se)) - (d + outBias[tg]);
            }
        }
        __syncthreads();
        {   // GRU: 2 j per block, K split 4x128
            const int tokb = sh_tok[gb];
            const float4* x4 = (const float4*)(emb + (size_t)tokb*H + gkq*128);
            const float4* h4 = (const float4*)(hin + (size_t)gb*H + gkq*128);
            float ir=0.f, iz=0.f, in_=0.f, hr=0.f, hz=0.f, hn=0.f;
            #pragma unroll 4
            for (int k=0;k<32;k++){
                const float4 xv = x4[k], hv = h4[k];
                ir  = dot4(ir , xv, gwir[k]);
                iz  = dot4(iz , xv, gwiz[k]);
                in_ = dot4(in_, xv, gwin[k]);
                hr  = dot4(hr , hv, gwhr[k]);
                hz  = dot4(hz , hv, gwhz[k]);
                hn  = dot4(hn , hv, gwhn[k]);
            }
            if (gkq){
                float* pp = smem + ((gkq-1)*64 + gj*32 + gb)*6;
                pp[0]=ir; pp[1]=iz; pp[2]=in_; pp[3]=hr; pp[4]=hz; pp[5]=hn;
            }
            __syncthreads();
            if (!gkq){
                #pragma unroll
                for (int q=0;q<3;q++){
                    const float* pp = smem + (q*64 + gj*32 + gb)*6;
                    ir+=pp[0]; iz+=pp[1]; in_+=pp[2]; hr+=pp[3]; hz+=pp[4]; hn+=pp[5];
                }
                const float r = sigmoidf_(ir + gbi_r + hr + gbh_r);
                const float z = sigmoidf_(iz + gbi_z + hz + gbh_z);
                const float n = tanhf(in_ + gbi_n + r*(hn + gbh_n));
                const float hprev = hin[(size_t)gb*H + jrow];
                hout[(size_t)gb*H + jrow] = (1.0f - z)*n + z*hprev;
            }
        }
        tgt_bar += NB; grid_sync(bar, tgt_bar);

        // ---------- phase S: scores[b][s] = hn . enc[b][s] --------------------
        {
            const int bS = bk & 31, sg = bk >> 5;
            const int sl = tid>>2, q = tid&3;
            const int s = sg*64 + sl;
            const float4* h4 = (const float4*)(hout + (size_t)bS*H + q*128);
            const float4* e4 = (const float4*)(enc_out + ((size_t)bS*S + s)*H + q*128);
            float a = 0.f;
            #pragma unroll 8
            for (int k=0;k<32;k++) a = dot4(a, h4[k], e4[k]);
            a += __shfl_xor(a, 1);
            a += __shfl_xor(a, 2);
            if (q == 0) scores[bS*S + s] = a;
        }
        tgt_bar += NB; grid_sync(bar, tgt_bar);

        // ---------- phase C: softmax + ctx ------------------------------------
        {
            const int bC = bk & 31, cg = bk >> 5;
            float* sh_w = smem; float* red = smem + 512; float* part = smem + 768;
            const float s0 = scores[bC*S + tid], s1 = scores[bC*S + tid + 256];
            red[tid] = fmaxf(s0,s1); __syncthreads();
            for (int off=128; off>0; off>>=1){ if (tid<off) red[tid]=fmaxf(red[tid],red[tid+off]); __syncthreads(); }
            const float M = red[0]; __syncthreads();
            const float e0 = expf(s0-M), e1 = expf(s1-M);
            red[tid] = e0+e1; __syncthreads();
            for (int off=128; off>0; off>>=1){ if (tid<off) red[tid]+=red[tid+off]; __syncthreads(); }
            const float inv = 1.0f/red[0];
            __syncthreads();
            sh_w[tid] = e0*inv; sh_w[tid+256] = e1*inv;
            __syncthreads();
            const int col = cg*64 + (tid & 63);
            const int sg2 = tid >> 6;
            const float* Ec = enc_out + (size_t)bC*S*H + col;
            float acc = 0.f;
            #pragma unroll 8
            for (int s2=sg2; s2<S; s2+=4) acc = fmaf(sh_w[s2], Ec[(size_t)s2*H], acc);
            part[tid] = acc; __syncthreads();
            if (tid < 64) ctxb[bC*512 + col] = part[tid]+part[tid+64]+part[tid+128]+part[tid+192];
        }
        tgt_bar += NB; grid_sync(bar, tgt_bar);

        // ---------- phase P: att_out = tanh([ctx,hn] @ attW.T + attb) ---------
        {
            const float* act = (gkq < 2) ? (ctxb + (size_t)gb*512 + gkq*256)
                                         : (hout + (size_t)gb*H + (gkq-2)*256);
            const float4* a4 = (const float4*)act;
            float acc = 0.f;
            #pragma unroll 8
            for (int k=0;k<64;k++) acc = dot4(acc, a4[k], pw[k]);
            if (gkq){
                smem[(gkq-1)*64 + gj*32 + gb] = acc;
            }
            __syncthreads();
            if (!gkq){
                acc += smem[0*64 + gj*32 + gb] + smem[1*64 + gj*32 + gb] + smem[2*64 + gj*32 + gb];
                att_out[(size_t)gb*H + jrow] = tanhf(acc + attb[jrow]);
            }
        }
        tgt_bar += NB; grid_sync(bar, tgt_bar);

        // ---------- phase L: logits partials (online softmax + argmax) --------
        if (bk < LCHUNK){
            const int rg = tid & 31, bg = tid >> 5;
            const int r0 = bk*LROWS + rg;
            const float4* w0 = (const float4*)(outW + (size_t)(r0     )*H);
            const float4* w1 = (const float4*)(outW + (size_t)(r0 + 32)*H);
            const float4* w2 = (const float4*)(outW + (size_t)(r0 + 64)*H);
            const float4* w3 = (const float4*)(outW + (size_t)(r0 + 96)*H);
            float4* sh4 = (float4*)smem;
            float acc[4][4];
            #pragma unroll
            for (int i=0;i<4;i++){ acc[i][0]=0.f; acc[i][1]=0.f; acc[i][2]=0.f; acc[i][3]=0.f; }

            for (int ph=0; ph<2; ph++){
                #pragma unroll
                for (int ii=0; ii<8; ii++){
                    const int f4 = tid + 256*ii;
                    const int bb = f4 >> 6, k4 = f4 & 63;
                    sh4[bb*(LDSPITCH/4) + k4] = ((const float4*)att_out)[(size_t)bb*(H/4) + ph*64 + k4];
                }
                __syncthreads();
                #pragma unroll 4
                for (int k=0;k<64;k++){
                    const float4 a0 = sh4[(bg*4+0)*(LDSPITCH/4) + k];
                    const float4 a1 = sh4[(bg*4+1)*(LDSPITCH/4) + k];
                    const float4 a2 = sh4[(bg*4+2)*(LDSPITCH/4) + k];
                    const float4 a3 = sh4[(bg*4+3)*(LDSPITCH/4) + k];
                    const int kk = ph*64 + k;
                    {   const float4 wv = w0[kk];
                        acc[0][0]=dot4(acc[0][0],wv,a0); acc[0][1]=dot4(acc[0][1],wv,a1);
                        acc[0][2]=dot4(acc[0][2],wv,a2); acc[0][3]=dot4(acc[0][3],wv,a3); }
                    {   const float4 wv = w1[kk];
                        acc[1][0]=dot4(acc[1][0],wv,a0); acc[1][1]=dot4(acc[1][1],wv,a1);
                        acc[1][2]=dot4(acc[1][2],wv,a2); acc[1][3]=dot4(acc[1][3],wv,a3); }
                    {   const float4 wv = w2[kk];
                        acc[2][0]=dot4(acc[2][0],wv,a0); acc[2][1]=dot4(acc[2][1],wv,a1);
                        acc[2][2]=dot4(acc[2][2],wv,a2); acc[2][3]=dot4(acc[2][3],wv,a3); }
                    {   const float4 wv = w3[kk];
                        acc[3][0]=dot4(acc[3][0],wv,a0); acc[3][1]=dot4(acc[3][1],wv,a1);
                        acc[3][2]=dot4(acc[3][2],wv,a2); acc[3][3]=dot4(acc[3][3],wv,a3); }
                }
                __syncthreads();
            }

            const float bias0 = outBias[r0], bias1 = outBias[r0+32], bias2 = outBias[r0+64], bias3 = outBias[r0+96];
            #pragma unroll
            for (int jb=0;jb<4;jb++){
                float l0 = acc[0][jb]+bias0, l1 = acc[1][jb]+bias1, l2 = acc[2][jb]+bias2, l3 = acc[3][jb]+bias3;
                float M = fmaxf(fmaxf(l0,l1), fmaxf(l2,l3));
                #pragma unroll
                for (int m=1;m<32;m<<=1) M = fmaxf(M, __shfl_xor(M, m));
                float sum = expf(l0-M)+expf(l1-M)+expf(l2-M)+expf(l3-M);
                #pragma unroll
                for (int m=1;m<32;m<<=1) sum += __shfl_xor(sum, m);
                float bv = l0; int bi = r0;
                if (l1 > bv){ bv=l1; bi=r0+32; }
                if (l2 > bv){ bv=l2; bi=r0+64; }
                if (l3 > bv){ bv=l3; bi=r0+96; }
                #pragma unroll
                for (int m=1;m<32;m<<=1){
                    const float ov = __shfl_xor(bv, m); const int oi = __shfl_xor(bi, m);
                    if (ov > bv || (ov == bv && oi < bi)){ bv=ov; bi=oi; }
                }
                if (rg == 0){
                    const int bb = bg*4 + jb;
                    pm[bb*LCHUNK + bk] = M;
                    ps[bb*LCHUNK + bk] = sum;
                    pidx[bb*LCHUNK + bk] = bi;
                }
            }
        }
        tgt_bar += NB; grid_sync(bar, tgt_bar);
    }

    // ---- epilogue: block 0 computes loss(T-1) and the final mean -------------
    if (bk == 0){
        const int mb = tid>>3, p = tid&7;
        float mm = -INFINITY;
        for (int c=p; c<LCHUNK; c+=8) mm = fmaxf(mm, pm[mb*LCHUNK+c]);
        #pragma unroll
        for (int m=1;m<8;m<<=1) mm = fmaxf(mm, __shfl_xor(mm, m));
        float se = 0.0f;
        for (int c=p; c<LCHUNK; c+=8) se += ps[mb*LCHUNK+c]*expf(pm[mb*LCHUNK+c]-mm);
        #pragma unroll
        for (int m=1;m<8;m<<=1) se += __shfl_xor(se, m);
        const int tg = target_seq[mb*T + (T-1)];
        const float4* ar = (const float4*)(att_out + (size_t)mb*H) + p*16;
        const float4* wr = (const float4*)(outW + (size_t)tg*H) + p*16;
        float d = 0.0f;
        #pragma unroll
        for (int k=0;k<16;k++) d = dot4(d, ar[k], wr[k]);
        #pragma unroll
        for (int m=1;m<8;m<<=1) d += __shfl_xor(d, m);
        if (p==0) lossb[mb] += (mm + logf(se)) - (d + outBias[tg]);
        __syncthreads();
        if (tid < B){
            float v = lossb[tid];
            for (int off=16; off>0; off>>=1) v += __shfl_down(v, off);
            if (tid == 0) out[0] = v / (float)(B*T);
        }
    }
}

extern "C" void kernel_launch(void* const* d_in, const int* in_sizes, int n_in,
                              void* d_out, int out_size, void* d_ws, size_t ws_size,
                              hipStream_t stream)
{
    const int*   input_seq  = (const int*)  d_in[0];
    const int*   target_seq = (const int*)  d_in[1];
    const float* emb    = (const float*)d_in[2];
    const float* efWih  = (const float*)d_in[3];
    const float* efWhh  = (const float*)d_in[4];
    const float* efbih  = (const float*)d_in[5];
    const float* efbhh  = (const float*)d_in[6];
    const float* ebWih  = (const float*)d_in[7];
    const float* ebWhh  = (const float*)d_in[8];
    const float* ebbih  = (const float*)d_in[9];
    const float* ebbhh  = (const float*)d_in[10];
    const float* dWih   = (const float*)d_in[11];
    const float* dWhh   = (const float*)d_in[12];
    const float* dbih   = (const float*)d_in[13];
    const float* dbhh   = (const float*)d_in[14];
    const float* attW   = (const float*)d_in[15];
    const float* attb   = (const float*)d_in[16];
    const float* outW   = (const float*)d_in[17];
    const float* outBias= (const float*)d_in[18];

    // workspace layout (floats); bars live in their own 256B region at the front
    float* ws      = (float*)d_ws;
    unsigned* bars = (unsigned*)ws;                         // [0]=enc bar, [32]=dec bar
    float* enc_out = ws + 64;                               // B*S*H
    float* outb    = enc_out + (size_t)B*S*H;               // B*S*H
    float* scores  = outb    + (size_t)B*S*H;               // B*S
    float* ctxb    = scores  + (size_t)B*S;                 // B*512
    float* attout  = ctxb    + (size_t)B*512;               // B*H
    float* pm      = attout  + (size_t)B*H;                 // B*LCHUNK
    float* ps      = pm      + (size_t)B*LCHUNK;            // B*LCHUNK
    int*   pidx    = (int*)(ps + (size_t)B*LCHUNK);         // B*LCHUNK
    float* hdec    = (float*)(pidx + (size_t)B*LCHUNK);     // 2*B*H
    float* lossb   = hdec    + (size_t)2*B*H;               // B

    hipMemsetAsync(bars, 0, 256, stream);

    enc_persistent<<<NB, NT, 0, stream>>>(input_seq, emb,
        efWih, efWhh, efbih, efbhh, ebWih, ebWhh, ebbih, ebbhh,
        enc_out, outb, hdec, bars);

    dec_persistent<<<NB, NT, 0, stream>>>(target_seq, emb,
        dWih, dWhh, dbih, dbhh, attW, attb, outW, outBias,
        enc_out, outb, hdec, scores, ctxb, attout,
        pm, ps, pidx, lossb, (float*)d_out, bars + 32);
}

// Round 4
// 36157.312 us; speedup vs baseline: 2.6289x; 2.6289x over previous
//
#include <hip/hip_runtime.h>
#include <math.h>

#define B 32
#define S 512
#define T 128
#define V 32000
#define H 512
#define NB 256          // persistent grid size (== CU count, co-resident)
#define NT 256
#define LCHUNK 250      // logits chunks: 250 blocks x 128 rows = 32000
#define LROWS 128
#define LDSPITCH 264    // 256 k-floats + 8 pad, 16B aligned

__device__ __forceinline__ float dot4(float acc, float4 a, float4 b){
    return fmaf(a.x,b.x, fmaf(a.y,b.y, fmaf(a.z,b.z, fmaf(a.w,b.w, acc))));
}
__device__ __forceinline__ float sigmoidf_(float x){ return 1.0f/(1.0f+expf(-x)); }

// ---- fast grid barrier: relaxed polling (no per-poll cache inv), one acquire at exit
__device__ __forceinline__ void bar_arrive(unsigned* bar){
    __syncthreads();                    // all block stores issued
    if (threadIdx.x == 0)
        __hip_atomic_fetch_add(bar, 1u, __ATOMIC_RELEASE, __HIP_MEMORY_SCOPE_AGENT);
}
__device__ __forceinline__ void bar_wait(unsigned* bar, unsigned target){
    if (threadIdx.x == 0){
        long guard = 0;
        while (__hip_atomic_load(bar, __ATOMIC_RELAXED, __HIP_MEMORY_SCOPE_AGENT) < target){
            __builtin_amdgcn_s_sleep(2);
            if (++guard > 200000000L) break;   // anti-hang valve
        }
        (void)__hip_atomic_load(bar, __ATOMIC_ACQUIRE, __HIP_MEMORY_SCOPE_AGENT); // single L1/L2 inv
    }
    __syncthreads();
}

// ================= persistent encoder ========================================
// 256 blocks: dir = bk&1, jg = bk>>1 (4 j per block). Per-dir barrier.
// 256 threads: b = tid&31, jj = (tid>>5)&3, kh = tid>>7 (K split 2x256).
// Weights LDS-resident (48 KB) -> immune to fence invalidation.
__global__ __launch_bounds__(NT, 1) void enc_persistent(
    const int* __restrict__ input_seq, const float* __restrict__ emb,
    const float* __restrict__ fWih, const float* __restrict__ fWhh,
    const float* __restrict__ fbih, const float* __restrict__ fbhh,
    const float* __restrict__ bWih, const float* __restrict__ bWhh,
    const float* __restrict__ bbih, const float* __restrict__ bbhh,
    float* enc_out, float* out_b, unsigned* bars)
{
    __shared__ float wlds[24*512];      // 4 j x 6 rows x 512 k
    __shared__ float shp[128*6];
    const int bk = blockIdx.x, tid = threadIdx.x;
    const int dir = bk & 1, jg = bk >> 1;
    const int b = tid & 31, jj = (tid>>5)&3, kh = tid>>7;
    const int j = jg*4 + jj;

    const float *Wih = dir? bWih : fWih;
    const float *Whh = dir? bWhh : fWhh;
    const float *bih = dir? bbih : fbih;
    const float *bhh = dir? bbhh : fbhh;
    float* outp = dir? out_b : enc_out;
    unsigned* bar = bars + dir*64;      // separate cache lines per dir

    // stage weights -> LDS (once)
    for (int r=0;r<24;r++){
        const int jr = jg*4 + (r/6);
        const int g  = r % 6;
        const float* src = (g<3) ? (Wih + ((size_t)g*H + jr)*H)
                                 : (Whh + ((size_t)(g-3)*H + jr)*H);
        for (int k=tid;k<H;k+=NT) wlds[r*512+k] = src[k];
    }
    __syncthreads();

    const float4* wx0 = (const float4*)(wlds + (jj*6+0)*512 + kh*256);
    const float4* wx1 = (const float4*)(wlds + (jj*6+1)*512 + kh*256);
    const float4* wx2 = (const float4*)(wlds + (jj*6+2)*512 + kh*256);
    const float4* wh0 = (const float4*)(wlds + (jj*6+3)*512 + kh*256);
    const float4* wh1 = (const float4*)(wlds + (jj*6+4)*512 + kh*256);
    const float4* wh2 = (const float4*)(wlds + (jj*6+5)*512 + kh*256);
    const float bi_r = bih[j], bi_z = bih[H+j], bi_n = bih[2*H+j];
    const float bh_r = bhh[j], bh_z = bhh[H+j], bh_n = bhh[2*H+j];

    for (int t=0; t<S; t++){
        const int pos  = dir ? (S-1-t) : t;
        const int hpos = dir ? (S-t)   : (t-1);
        const int tokb = input_seq[b*S + pos];
        const float4* x4 = (const float4*)(emb + (size_t)tokb*H + kh*256);

        // x-part BEFORE the wait (no dependence on h(t-1)) — overlaps barrier skew
        float ir=0.f, iz=0.f, in_=0.f;
        #pragma unroll 4
        for (int k=0;k<64;k++){
            const float4 xv = x4[k];
            ir  = dot4(ir , xv, wx0[k]);
            iz  = dot4(iz , xv, wx1[k]);
            in_ = dot4(in_, xv, wx2[k]);
        }

        if (t > 0) bar_wait(bar, (unsigned)t*128u);

        float hr=0.f, hz=0.f, hn=0.f;
        if (t > 0){
            const float4* h4 = (const float4*)(outp + ((size_t)b*S + hpos)*H + kh*256);
            #pragma unroll 4
            for (int k=0;k<64;k++){
                const float4 hv = h4[k];
                hr = dot4(hr, hv, wh0[k]);
                hz = dot4(hz, hv, wh1[k]);
                hn = dot4(hn, hv, wh2[k]);
            }
        }
        if (kh){
            float* p = shp + (jj*32 + b)*6;
            p[0]=ir; p[1]=iz; p[2]=in_; p[3]=hr; p[4]=hz; p[5]=hn;
        }
        __syncthreads();
        if (!kh){
            const float* p = shp + (jj*32 + b)*6;
            ir+=p[0]; iz+=p[1]; in_+=p[2]; hr+=p[3]; hz+=p[4]; hn+=p[5];
            float hprev = (t>0) ? outp[((size_t)b*S + hpos)*H + j] : 0.0f;
            const float r = sigmoidf_(ir + bi_r + hr + bh_r);
            const float z = sigmoidf_(iz + bi_z + hz + bh_z);
            const float n = tanhf(in_ + bi_n + r*(hn + bh_n));
            outp[((size_t)b*S + pos)*H + j] = (1.0f - z)*n + z*hprev;
        }
        bar_arrive(bar);
    }
}

// ================= persistent decoder ========================================
__global__ __launch_bounds__(NT, 1) void dec_persistent(
    const int* __restrict__ target_seq, const float* __restrict__ emb,
    const float* __restrict__ dWih, const float* __restrict__ dWhh,
    const float* __restrict__ dbih, const float* __restrict__ dbhh,
    const float* __restrict__ attW, const float* __restrict__ attb,
    const float* __restrict__ outW, const float* __restrict__ outBias,
    float* enc_out, const float* out_b,
    float* hdec, float* scores, float* ctxb, float* att_out,
    float* pm, float* ps, int* pidx, float* lossb,
    float* out, unsigned* bar)
{
    __shared__ __align__(16) float smem[32*LDSPITCH];   // 33.8 KB scratch (phase-local)
    __shared__ float wg[12*512];                        // GRU weights: 2 j x 6 rows
    __shared__ float wp[2*1024];                        // proj weights: 2 rows x 2H
    __shared__ int sh_tok[B];
    const int bk = blockIdx.x, tid = threadIdx.x;
    unsigned tgt = 0;
#define GSYNC() do { bar_arrive(bar); tgt += NB; bar_wait(bar, tgt); } while(0)

    // stage decoder weights -> LDS (once)
    for (int r=0;r<12;r++){
        const int jr = bk*2 + (r/6);
        const int g  = r % 6;
        const float* src = (g<3) ? (dWih + ((size_t)g*H + jr)*H)
                                 : (dWhh + ((size_t)(g-3)*H + jr)*H);
        for (int k=tid;k<H;k+=NT) wg[r*512+k] = src[k];
    }
    for (int r=0;r<2;r++){
        const float* src = attW + (size_t)(bk*2+r)*(2*H);
        for (int k=tid;k<2*H;k+=NT) wp[r*1024+k] = src[k];
    }

    // ---- phase A: hdec0 = hf_last + hb_last (pre-combine values); loss init --
    {
        const int gid = bk*NT + tid;
        if (gid < B*H){
            const int bb = gid >> 9, jq = gid & 511;
            hdec[gid] = enc_out[((size_t)bb*S + (S-1))*H + jq] + out_b[((size_t)bb*S)*H + jq];
        }
        if (bk==0 && tid<B) lossb[tid] = 0.0f;
    }
    GSYNC();

    // ---- phase B: combine enc_out += out_b ----
    {
        float4* e4 = (float4*)enc_out; const float4* o4 = (const float4*)out_b;
        for (size_t i = (size_t)bk*NT + tid; i < (size_t)B*S*H/4; i += (size_t)NB*NT){
            float4 x = e4[i]; const float4 y = o4[i];
            x.x+=y.x; x.y+=y.y; x.z+=y.z; x.w+=y.w; e4[i]=x;
        }
    }
    GSYNC();

    const int gb = tid & 31, gj = (tid>>5)&1, gkq = tid>>6;
    const int jrow = bk*2 + gj;
    const float4* gwir = (const float4*)(wg + (gj*6+0)*512 + gkq*128);
    const float4* gwiz = (const float4*)(wg + (gj*6+1)*512 + gkq*128);
    const float4* gwin = (const float4*)(wg + (gj*6+2)*512 + gkq*128);
    const float4* gwhr = (const float4*)(wg + (gj*6+3)*512 + gkq*128);
    const float4* gwhz = (const float4*)(wg + (gj*6+4)*512 + gkq*128);
    const float4* gwhn = (const float4*)(wg + (gj*6+5)*512 + gkq*128);
    const float gbi_r = dbih[jrow], gbi_z = dbih[H+jrow], gbi_n = dbih[2*H+jrow];
    const float gbh_r = dbhh[jrow], gbh_z = dbhh[H+jrow], gbh_n = dbhh[2*H+jrow];
    const float4* pw = (const float4*)(wp + gj*1024 + gkq*256);

    for (int t=0; t<T; t++){
        float* hin  = hdec + (size_t)(t&1)*B*H;
        float* hout = hdec + (size_t)((t+1)&1)*B*H;

        // ---------- phase G: merge(t-1) -> tokens (+loss by blk0), then GRU --
        if (t == 0){
            if (tid < B) sh_tok[tid] = 1;     // SOS
        } else {
            const int mb = tid>>3, p = tid&7;
            float bv = -INFINITY; int ai = 0x7FFFFFFF;
            for (int c=p; c<LCHUNK; c+=8){
                const float v = pm[mb*LCHUNK + c];
                if (v > bv){ bv = v; ai = pidx[mb*LCHUNK + c]; }
            }
            #pragma unroll
            for (int m=1; m<8; m<<=1){
                const float ov = __shfl_xor(bv, m); const int oi = __shfl_xor(ai, m);
                if (ov > bv || (ov == bv && oi < ai)){ bv = ov; ai = oi; }
            }
            if (p==0) sh_tok[mb] = ai;
            if (bk == 0){
                float mm = -INFINITY;
                for (int c=p; c<LCHUNK; c+=8) mm = fmaxf(mm, pm[mb*LCHUNK+c]);
                #pragma unroll
                for (int m=1;m<8;m<<=1) mm = fmaxf(mm, __shfl_xor(mm, m));
                float se = 0.0f;
                for (int c=p; c<LCHUNK; c+=8) se += ps[mb*LCHUNK+c]*expf(pm[mb*LCHUNK+c]-mm);
                #pragma unroll
                for (int m=1;m<8;m<<=1) se += __shfl_xor(se, m);
                const int tg = target_seq[mb*T + (t-1)];
                const float4* ar = (const float4*)(att_out + (size_t)mb*H) + p*16;
                const float4* wr = (const float4*)(outW + (size_t)tg*H) + p*16;
                float d = 0.0f;
                #pragma unroll
                for (int k=0;k<16;k++) d = dot4(d, ar[k], wr[k]);
                #pragma unroll
                for (int m=1;m<8;m<<=1) d += __shfl_xor(d, m);
                if (p==0) lossb[mb] += (mm + logf(se)) - (d + outBias[tg]);
            }
        }
        __syncthreads();
        {   // GRU: 2 j per block, K split 4x128, weights from LDS
            const int tokb = sh_tok[gb];
            const float4* x4 = (const float4*)(emb + (size_t)tokb*H + gkq*128);
            const float4* h4 = (const float4*)(hin + (size_t)gb*H + gkq*128);
            float ir=0.f, iz=0.f, in_=0.f, hr=0.f, hz=0.f, hn=0.f;
            #pragma unroll 4
            for (int k=0;k<32;k++){
                const float4 xv = x4[k], hv = h4[k];
                ir  = dot4(ir , xv, gwir[k]);
                iz  = dot4(iz , xv, gwiz[k]);
                in_ = dot4(in_, xv, gwin[k]);
                hr  = dot4(hr , hv, gwhr[k]);
                hz  = dot4(hz , hv, gwhz[k]);
                hn  = dot4(hn , hv, gwhn[k]);
            }
            if (gkq){
                float* pp = smem + ((gkq-1)*64 + gj*32 + gb)*6;
                pp[0]=ir; pp[1]=iz; pp[2]=in_; pp[3]=hr; pp[4]=hz; pp[5]=hn;
            }
            __syncthreads();
            if (!gkq){
                #pragma unroll
                for (int q=0;q<3;q++){
                    const float* pp = smem + (q*64 + gj*32 + gb)*6;
                    ir+=pp[0]; iz+=pp[1]; in_+=pp[2]; hr+=pp[3]; hz+=pp[4]; hn+=pp[5];
                }
                const float r = sigmoidf_(ir + gbi_r + hr + gbh_r);
                const float z = sigmoidf_(iz + gbi_z + hz + gbh_z);
                const float n = tanhf(in_ + gbi_n + r*(hn + gbh_n));
                const float hprev = hin[(size_t)gb*H + jrow];
                hout[(size_t)gb*H + jrow] = (1.0f - z)*n + z*hprev;
            }
        }
        GSYNC();

        // ---------- phase S: scores[b][s] = hn . enc[b][s] --------------------
        {
            const int bS = bk & 31, sg = bk >> 5;
            const int sl = tid>>2, q = tid&3;
            const int s = sg*64 + sl;
            const float4* h4 = (const float4*)(hout + (size_t)bS*H + q*128);
            const float4* e4 = (const float4*)(enc_out + ((size_t)bS*S + s)*H + q*128);
            float a = 0.f;
            #pragma unroll 8
            for (int k=0;k<32;k++) a = dot4(a, h4[k], e4[k]);
            a += __shfl_xor(a, 1);
            a += __shfl_xor(a, 2);
            if (q == 0) scores[bS*S + s] = a;
        }
        GSYNC();

        // ---------- phase C: softmax + ctx ------------------------------------
        {
            const int bC = bk & 31, cg = bk >> 5;
            float* sh_w = smem; float* red = smem + 512; float* part = smem + 768;
            const float s0 = scores[bC*S + tid], s1 = scores[bC*S + tid + 256];
            red[tid] = fmaxf(s0,s1); __syncthreads();
            for (int off=128; off>0; off>>=1){ if (tid<off) red[tid]=fmaxf(red[tid],red[tid+off]); __syncthreads(); }
            const float M = red[0]; __syncthreads();
            const float e0 = expf(s0-M), e1 = expf(s1-M);
            red[tid] = e0+e1; __syncthreads();
            for (int off=128; off>0; off>>=1){ if (tid<off) red[tid]+=red[tid+off]; __syncthreads(); }
            const float inv = 1.0f/red[0];
            __syncthreads();
            sh_w[tid] = e0*inv; sh_w[tid+256] = e1*inv;
            __syncthreads();
            const int col = cg*64 + (tid & 63);
            const int sg2 = tid >> 6;
            const float* Ec = enc_out + (size_t)bC*S*H + col;
            float acc = 0.f;
            #pragma unroll 8
            for (int s2=sg2; s2<S; s2+=4) acc = fmaf(sh_w[s2], Ec[(size_t)s2*H], acc);
            part[tid] = acc; __syncthreads();
            if (tid < 64) ctxb[bC*512 + col] = part[tid]+part[tid+64]+part[tid+128]+part[tid+192];
        }
        GSYNC();

        // ---------- phase P: att_out = tanh([ctx,hn] @ attW.T + attb) ---------
        {
            const float* act = (gkq < 2) ? (ctxb + (size_t)gb*512 + gkq*256)
                                         : (hout + (size_t)gb*H + (gkq-2)*256);
            const float4* a4 = (const float4*)act;
            float acc = 0.f;
            #pragma unroll 8
            for (int k=0;k<64;k++) acc = dot4(acc, a4[k], pw[k]);
            if (gkq){
                smem[(gkq-1)*64 + gj*32 + gb] = acc;
            }
            __syncthreads();
            if (!gkq){
                acc += smem[0*64 + gj*32 + gb] + smem[1*64 + gj*32 + gb] + smem[2*64 + gj*32 + gb];
                att_out[(size_t)gb*H + jrow] = tanhf(acc + attb[jrow]);
            }
        }
        GSYNC();

        // ---------- phase L: logits partials (online softmax + argmax) --------
        if (bk < LCHUNK){
            const int rg = tid & 31, bg = tid >> 5;
            const int r0 = bk*LROWS + rg;
            const float4* w0 = (const float4*)(outW + (size_t)(r0     )*H);
            const float4* w1 = (const float4*)(outW + (size_t)(r0 + 32)*H);
            const float4* w2 = (const float4*)(outW + (size_t)(r0 + 64)*H);
            const float4* w3 = (const float4*)(outW + (size_t)(r0 + 96)*H);
            float4* sh4 = (float4*)smem;
            float acc[4][4];
            #pragma unroll
            for (int i=0;i<4;i++){ acc[i][0]=0.f; acc[i][1]=0.f; acc[i][2]=0.f; acc[i][3]=0.f; }

            for (int ph=0; ph<2; ph++){
                #pragma unroll
                for (int ii=0; ii<8; ii++){
                    const int f4 = tid + 256*ii;
                    const int bb = f4 >> 6, k4 = f4 & 63;
                    sh4[bb*(LDSPITCH/4) + k4] = ((const float4*)att_out)[(size_t)bb*(H/4) + ph*64 + k4];
                }
                __syncthreads();
                #pragma unroll 4
                for (int k=0;k<64;k++){
                    const float4 a0 = sh4[(bg*4+0)*(LDSPITCH/4) + k];
                    const float4 a1 = sh4[(bg*4+1)*(LDSPITCH/4) + k];
                    const float4 a2 = sh4[(bg*4+2)*(LDSPITCH/4) + k];
                    const float4 a3 = sh4[(bg*4+3)*(LDSPITCH/4) + k];
                    const int kk = ph*64 + k;
                    {   const float4 wv = w0[kk];
                        acc[0][0]=dot4(acc[0][0],wv,a0); acc[0][1]=dot4(acc[0][1],wv,a1);
                        acc[0][2]=dot4(acc[0][2],wv,a2); acc[0][3]=dot4(acc[0][3],wv,a3); }
                    {   const float4 wv = w1[kk];
                        acc[1][0]=dot4(acc[1][0],wv,a0); acc[1][1]=dot4(acc[1][1],wv,a1);
                        acc[1][2]=dot4(acc[1][2],wv,a2); acc[1][3]=dot4(acc[1][3],wv,a3); }
                    {   const float4 wv = w2[kk];
                        acc[2][0]=dot4(acc[2][0],wv,a0); acc[2][1]=dot4(acc[2][1],wv,a1);
                        acc[2][2]=dot4(acc[2][2],wv,a2); acc[2][3]=dot4(acc[2][3],wv,a3); }
                    {   const float4 wv = w3[kk];
                        acc[3][0]=dot4(acc[3][0],wv,a0); acc[3][1]=dot4(acc[3][1],wv,a1);
                        acc[3][2]=dot4(acc[3][2],wv,a2); acc[3][3]=dot4(acc[3][3],wv,a3); }
                }
                __syncthreads();
            }

            const float bias0 = outBias[r0], bias1 = outBias[r0+32], bias2 = outBias[r0+64], bias3 = outBias[r0+96];
            #pragma unroll
            for (int jb=0;jb<4;jb++){
                float l0 = acc[0][jb]+bias0, l1 = acc[1][jb]+bias1, l2 = acc[2][jb]+bias2, l3 = acc[3][jb]+bias3;
                float M = fmaxf(fmaxf(l0,l1), fmaxf(l2,l3));
                #pragma unroll
                for (int m=1;m<32;m<<=1) M = fmaxf(M, __shfl_xor(M, m));
                float sum = expf(l0-M)+expf(l1-M)+expf(l2-M)+expf(l3-M);
                #pragma unroll
                for (int m=1;m<32;m<<=1) sum += __shfl_xor(sum, m);
                float bv = l0; int bi = r0;
                if (l1 > bv){ bv=l1; bi=r0+32; }
                if (l2 > bv){ bv=l2; bi=r0+64; }
                if (l3 > bv){ bv=l3; bi=r0+96; }
                #pragma unroll
                for (int m=1;m<32;m<<=1){
                    const float ov = __shfl_xor(bv, m); const int oi = __shfl_xor(bi, m);
                    if (ov > bv || (ov == bv && oi < bi)){ bv=ov; bi=oi; }
                }
                if (rg == 0){
                    const int bb = bg*4 + jb;
                    pm[bb*LCHUNK + bk] = M;
                    ps[bb*LCHUNK + bk] = sum;
                    pidx[bb*LCHUNK + bk] = bi;
                }
            }
        }
        GSYNC();
    }

    // ---- epilogue: block 0 computes loss(T-1) and the final mean -------------
    if (bk == 0){
        const int mb = tid>>3, p = tid&7;
        float mm = -INFINITY;
        for (int c=p; c<LCHUNK; c+=8) mm = fmaxf(mm, pm[mb*LCHUNK+c]);
        #pragma unroll
        for (int m=1;m<8;m<<=1) mm = fmaxf(mm, __shfl_xor(mm, m));
        float se = 0.0f;
        for (int c=p; c<LCHUNK; c+=8) se += ps[mb*LCHUNK+c]*expf(pm[mb*LCHUNK+c]-mm);
        #pragma unroll
        for (int m=1;m<8;m<<=1) se += __shfl_xor(se, m);
        const int tg = target_seq[mb*T + (T-1)];
        const float4* ar = (const float4*)(att_out + (size_t)mb*H) + p*16;
        const float4* wr = (const float4*)(outW + (size_t)tg*H) + p*16;
        float d = 0.0f;
        #pragma unroll
        for (int k=0;k<16;k++) d = dot4(d, ar[k], wr[k]);
        #pragma unroll
        for (int m=1;m<8;m<<=1) d += __shfl_xor(d, m);
        if (p==0) lossb[mb] += (mm + logf(se)) - (d + outBias[tg]);
        __syncthreads();
        if (tid < B){
            float v = lossb[tid];
            for (int off=16; off>0; off>>=1) v += __shfl_down(v, off);
            if (tid == 0) out[0] = v / (float)(B*T);
        }
    }
#undef GSYNC
}

extern "C" void kernel_launch(void* const* d_in, const int* in_sizes, int n_in,
                              void* d_out, int out_size, void* d_ws, size_t ws_size,
                              hipStream_t stream)
{
    const int*   input_seq  = (const int*)  d_in[0];
    const int*   target_seq = (const int*)  d_in[1];
    const float* emb    = (const float*)d_in[2];
    const float* efWih  = (const float*)d_in[3];
    const float* efWhh  = (const float*)d_in[4];
    const float* efbih  = (const float*)d_in[5];
    const float* efbhh  = (const float*)d_in[6];
    const float* ebWih  = (const float*)d_in[7];
    const float* ebWhh  = (const float*)d_in[8];
    const float* ebbih  = (const float*)d_in[9];
    const float* ebbhh  = (const float*)d_in[10];
    const float* dWih   = (const float*)d_in[11];
    const float* dWhh   = (const float*)d_in[12];
    const float* dbih   = (const float*)d_in[13];
    const float* dbhh   = (const float*)d_in[14];
    const float* attW   = (const float*)d_in[15];
    const float* attb   = (const float*)d_in[16];
    const float* outW   = (const float*)d_in[17];
    const float* outBias= (const float*)d_in[18];

    // workspace layout (floats); barrier counters in their own 1 KB region
    float* ws      = (float*)d_ws;
    unsigned* bars = (unsigned*)ws;                         // [0]=enc d0, [64]=enc d1, [128]=dec
    float* enc_out = ws + 256;                              // B*S*H
    float* outb    = enc_out + (size_t)B*S*H;               // B*S*H
    float* scores  = outb    + (size_t)B*S*H;               // B*S
    float* ctxb    = scores  + (size_t)B*S;                 // B*512
    float* attout  = ctxb    + (size_t)B*512;               // B*H
    float* pm      = attout  + (size_t)B*H;                 // B*LCHUNK
    float* ps      = pm      + (size_t)B*LCHUNK;            // B*LCHUNK
    int*   pidx    = (int*)(ps + (size_t)B*LCHUNK);         // B*LCHUNK
    float* hdec    = (float*)(pidx + (size_t)B*LCHUNK);     // 2*B*H
    float* lossb   = hdec    + (size_t)2*B*H;               // B

    hipMemsetAsync(bars, 0, 1024, stream);

    enc_persistent<<<NB, NT, 0, stream>>>(input_seq, emb,
        efWih, efWhh, efbih, efbhh, ebWih, ebWhh, ebbih, ebbhh,
        enc_out, outb, bars);

    dec_persistent<<<NB, NT, 0, stream>>>(target_seq, emb,
        dWih, dWhh, dbih, dbhh, attW, attb, outW, outBias,
        enc_out, outb, hdec, scores, ctxb, attout,
        pm, ps, pidx, lossb, (float*)d_out, bars + 128);
}